// Round 1
// 63.600 us; speedup vs baseline: 1.0183x; 1.0183x over previous
//
#include <hip/hip_runtime.h>

#define NQ 16

// c*v0 - i*s*v1   (RX butterfly contribution)
__device__ __forceinline__ float2 rxmix(float2 v0, float2 v1, float c, float s) {
    return make_float2(c * v0.x + s * v1.y, c * v0.y - s * v1.x);
}

// One block per sample, 256 threads (4 waves).
//
// state = C2 R2 C1 R1 |0>;  RX angles merge (R1 absorbs layer-0), ring CNOTs are
// basis permutations, C2 is absorbed into the measurement (nested Z-string masks).
// C1 chi is rank-4 across the hi(0..7)/lo(8..15) cut:
//   X_{2a+t}(h) = A_t(h) [h&1==a],  Y_{2a+b}(l) = B_a(l) [l&1==b].
// R2 = (wires0..6)(wire7) x (wires8..14)(wire15); wires 0..6/8..14 act on bits 7..1
// and commute with the bit-0 projector, so we rotate only 4 arrays (A0,A1,B0,B1)
// and apply wires 7/15 as scalar 2x2 factors in the product phase.
// Gram sums G[side][m][pp] = sum_e sgn_m(e) u_p(e) conj(u_q(e)) are computed via a
// 64-point Walsh-Hadamard over lane bits (shfl_xor butterflies) + 4-wave combine.
extern "C" __global__ __launch_bounds__(256)
void qsim_kernel(const float* __restrict__ z,
                 const float* __restrict__ params,
                 const float* __restrict__ ew,
                 float* __restrict__ out)
{
    const int b    = blockIdx.x;
    const int tid  = threadIdx.x;
    const int lane = tid & 63;
    const int wv   = tid >> 6;        // wave id = array id (0:A0 1:A1 2:B0 3:B1)

    __shared__ float c1[NQ], s1[NQ], cw[NQ], sw[NQ];
    __shared__ __align__(16) float2 V4[4][258];     // rotated arrays, padded rows
    __shared__ __align__(16) float  PART[4][7][33]; // [wave][low-mask idx][array], padded
    __shared__ float2 G[2][9][10];

    if (tid < 32) {
        const int q = tid & 15;
        if (tid < 16) {
            // embed + layer0 merged
            float phi = 0.5f * (z[b * NQ + q] + params[q] + ew[q]);
            float ss, cc;
            sincosf(phi, &ss, &cc);
            c1[q] = cc; s1[q] = ss;
        } else {
            float w = 0.5f * ew[NQ + q];  // layer1 RX
            float ss, cc;
            sincosf(w, &ss, &cc);
            cw[q] = cc; sw[q] = ss;
        }
    }
    __syncthreads();

    const bool hiw = (wv < 2);
    const int  par = wv & 1;          // t (hi) or a (lo) parameter of my array
    const int  wb  = hiw ? 0 : 8;

    // ---- Step 2: build my array's 4 elements e = (k<<6)|lane ----
    // Factorization: with e = (k<<6)|lane, a=k>>1, b=k&1, b5=lane>>5:
    //   wire wb+0: eb = a ^ par
    //   wire wb+1: eb = (a^b) ^ (hiw ? par : 0)
    //   wire wb+2: eb = b ^ b5
    //   wire wb+3+j (j=0..4): eb = graycode(lane) bit (4-j)   [lane-only]
    const int b5 = (lane >> 5) & 1;
    const int gl = (lane ^ (lane >> 1)) & 31;
    float t0 = ((gl >> 4) & 1) ? s1[wb + 3] : c1[wb + 3];
    float t1 = ((gl >> 3) & 1) ? s1[wb + 4] : c1[wb + 4];
    float t2 = ((gl >> 2) & 1) ? s1[wb + 5] : c1[wb + 5];
    float t3 = ((gl >> 1) & 1) ? s1[wb + 6] : c1[wb + 6];
    float t4 = ( gl       & 1) ? s1[wb + 7] : c1[wb + 7];
    const float laneMag = (t0 * t1) * (t2 * t3) * t4;  // tree: depth 3
    const int   laneKK  = __popc(gl);

    // shared 2-entry tables for the k-dependent wires
    const int p1 = hiw ? par : 0;
    float w0v0 = par ? s1[wb]     : c1[wb];       // a=0
    float w0v1 = par ? c1[wb]     : s1[wb];       // a=1
    float w1v0 = p1  ? s1[wb + 1] : c1[wb + 1];   // a^b=0
    float w1v1 = p1  ? c1[wb + 1] : s1[wb + 1];   // a^b=1
    float m2v0 = b5  ? s1[wb + 2] : c1[wb + 2];   // b=0
    float m2v1 = b5  ? c1[wb + 2] : s1[wb + 2];   // b=1

    float2 v[4];
#pragma unroll
    for (int k = 0; k < 4; ++k) {
        const int a = k >> 1, bb = k & 1, ab = a ^ bb;
        float wa = a  ? w0v1 : w0v0;
        float wc = ab ? w1v1 : w1v0;
        float wd = bb ? m2v1 : m2v0;
        float mag = laneMag * ((wa * wc) * wd);
        int kk = laneKK + (a ^ par) + (ab ^ p1) + (bb ^ b5);
        float sg = (kk & 2) ? -mag : mag;
        v[k] = (kk & 1) ? make_float2(0.f, -sg) : make_float2(sg, 0.f);
    }

    // ---- Step 3: rotate through 7 wires (bits 7..1). Wave-uniform angles. ----
    {   // bit 7 (wire wb+0): pairs (0,2),(1,3)
        float c = cw[wb + 0], s = sw[wb + 0];
        float2 n0 = rxmix(v[0], v[2], c, s), n2 = rxmix(v[2], v[0], c, s);
        float2 n1 = rxmix(v[1], v[3], c, s), n3 = rxmix(v[3], v[1], c, s);
        v[0] = n0; v[1] = n1; v[2] = n2; v[3] = n3;
    }
    {   // bit 6 (wire wb+1): pairs (0,1),(2,3)
        float c = cw[wb + 1], s = sw[wb + 1];
        float2 n0 = rxmix(v[0], v[1], c, s), n1 = rxmix(v[1], v[0], c, s);
        float2 n2 = rxmix(v[2], v[3], c, s), n3 = rxmix(v[3], v[2], c, s);
        v[0] = n0; v[1] = n1; v[2] = n2; v[3] = n3;
    }
#pragma unroll
    for (int bbit = 5; bbit >= 1; --bbit) {   // wires wb+2..wb+6
        float c = cw[wb + 7 - bbit], s = sw[wb + 7 - bbit];
        int m = 1 << bbit;
#pragma unroll
        for (int k = 0; k < 4; ++k) {
            float px = __shfl_xor(v[k].x, m);
            float py = __shfl_xor(v[k].y, m);
            v[k] = make_float2(c * v[k].x + s * py, c * v[k].y - s * px);
        }
    }
#pragma unroll
    for (int k = 0; k < 4; ++k) V4[wv][(k << 6) | lane] = v[k];
    __syncthreads();

    // ---- Step 4a: per-element sector values + pair products ----
    const int e0 = tid & 1, j2 = tid & ~1;
    float4 rA0 = *(const float4*)&V4[0][j2];   // (alpha0, beta0)
    float4 rA1 = *(const float4*)&V4[1][j2];   // (alpha1, beta1)
    float4 rB0 = *(const float4*)&V4[2][j2];   // (gamma0, delta0)
    float4 rB1 = *(const float4*)&V4[3][j2];   // (gamma1, delta1)
    float c7 = cw[7], s7 = sw[7], c15 = cw[15], s15 = sw[15];

    float2 x[4], yv[4];
    {
        float2 a0 = make_float2(rA0.x, rA0.y), b0 = make_float2(rA0.z, rA0.w);
        float2 a1 = make_float2(rA1.x, rA1.y), b1 = make_float2(rA1.z, rA1.w);
        if (e0 == 0) {  // x[2a+t]: a=0 -> c7*alpha_t ; a=1 -> -i s7 * beta_t
            x[0] = make_float2(c7 * a0.x, c7 * a0.y);
            x[1] = make_float2(c7 * a1.x, c7 * a1.y);
            x[2] = make_float2(s7 * b0.y, -s7 * b0.x);
            x[3] = make_float2(s7 * b1.y, -s7 * b1.x);
        } else {
            x[0] = make_float2(s7 * a0.y, -s7 * a0.x);
            x[1] = make_float2(s7 * a1.y, -s7 * a1.x);
            x[2] = make_float2(c7 * b0.x, c7 * b0.y);
            x[3] = make_float2(c7 * b1.x, c7 * b1.y);
        }
        float2 g0 = make_float2(rB0.x, rB0.y), d0 = make_float2(rB0.z, rB0.w);
        float2 g1 = make_float2(rB1.x, rB1.y), d1 = make_float2(rB1.z, rB1.w);
        if (e0 == 0) {  // y[2a+b]: b=0 -> c15*gamma_a ; b=1 -> -i s15 * delta_a
            yv[0] = make_float2(c15 * g0.x, c15 * g0.y);
            yv[2] = make_float2(c15 * g1.x, c15 * g1.y);
            yv[1] = make_float2(s15 * d0.y, -s15 * d0.x);
            yv[3] = make_float2(s15 * d1.y, -s15 * d1.x);
        } else {
            yv[0] = make_float2(s15 * g0.y, -s15 * g0.x);
            yv[2] = make_float2(s15 * g1.y, -s15 * g1.x);
            yv[1] = make_float2(c15 * d0.x, c15 * d0.y);
            yv[3] = make_float2(c15 * d1.x, c15 * d1.y);
        }
    }

    float wr[32];
    {
        float2 *p = x;
#pragma unroll
        for (int side = 0; side < 2; ++side, p = yv) {
            int o = side * 16;
            wr[o + 0] = p[0].x * p[0].x + p[0].y * p[0].y;
            wr[o + 1] = p[1].x * p[1].x + p[1].y * p[1].y;
            wr[o + 2] = p[2].x * p[2].x + p[2].y * p[2].y;
            wr[o + 3] = p[3].x * p[3].x + p[3].y * p[3].y;
            wr[o + 4]  = p[0].x * p[1].x + p[0].y * p[1].y;
            wr[o + 5]  = p[0].y * p[1].x - p[0].x * p[1].y;
            wr[o + 6]  = p[0].x * p[2].x + p[0].y * p[2].y;
            wr[o + 7]  = p[0].y * p[2].x - p[0].x * p[2].y;
            wr[o + 8]  = p[0].x * p[3].x + p[0].y * p[3].y;
            wr[o + 9]  = p[0].y * p[3].x - p[0].x * p[3].y;
            wr[o + 10] = p[1].x * p[2].x + p[1].y * p[2].y;
            wr[o + 11] = p[1].y * p[2].x - p[1].x * p[2].y;
            wr[o + 12] = p[1].x * p[3].x + p[1].y * p[3].y;
            wr[o + 13] = p[1].y * p[3].x - p[1].x * p[3].y;
            wr[o + 14] = p[2].x * p[3].x + p[2].y * p[3].y;
            wr[o + 15] = p[2].y * p[3].x - p[2].x * p[3].y;
        }
    }

    // ---- Step 4b: 64-point WHT over lane bits: lane L ends with signed sum
    //      sum_l (-1)^popc(L&l) wr(l) for every array ----
#pragma unroll
    for (int lev = 0; lev < 6; ++lev) {
        int m = 1 << lev;
        float s = (lane & m) ? -1.f : 1.f;
#pragma unroll
        for (int a = 0; a < 32; ++a) {
            float wp = __shfl_xor(wr[a], m);
            wr[a] = fmaf(s, wr[a], wp);
        }
    }
    {   // needed low-6 sign patterns: top-down prefix masks of bits 5..0.
        // lane is a prefix mask iff lane == (63 >> (6-p)) << (6-p), p = popc(lane);
        // its pattern index is then simply p.
        const int p = __popc(lane);
        if (lane == ((63 >> (6 - p)) << (6 - p))) {
#pragma unroll
            for (int a = 0; a < 32; ++a) PART[wv][p][a] = wr[a];
        }
    }
    __syncthreads();

    // ---- Step 4c: combine waves (bits 6,7) into G[side][m][pp] ----
    if (tid < 180) {
        int side = tid / 90, rest = tid - side * 90;
        int pp = rest / 9, m = rest - pp * 9;
        int M;
        if (side == 0) M = (m < 8) ? (((1 << (m + 1)) - 1) << (7 - m)) : 0x7F;
        else           M = (m == 0) ? 0 : (((1 << m) - 1) << (8 - m));
        int low = M & 63, hi2 = M >> 6;
        int li2 = __popc(low);                       // low is always a prefix mask
        int rs   = (int)((0x3E2CA18640ULL >> (4 * pp)) & 0xF);
        bool diag = (0x291 >> pp) & 1;               // pp in {0,4,7,9}
        float gr = 0.f, gi = 0.f;
#pragma unroll
        for (int w2 = 0; w2 < 4; ++w2) {
            float s = (__popc(hi2 & w2) & 1) ? -1.f : 1.f;
            gr = fmaf(s, PART[w2][li2][side * 16 + rs], gr);
            if (!diag) gi = fmaf(s, PART[w2][li2][side * 16 + rs + 1], gi);
        }
        G[side][m][pp] = make_float2(gr, gi);
    }
    __syncthreads();

    // ---- Step 5: out[i] = sum_pp w_pp * Re(Gh * Gl) ----
    if (tid < NQ) {
        const int i = tid;
        int hm, lm;
        if (i == 0)      { hm = 8; lm = 8; }     // Z-string {1..15}
        else if (i <= 7) { hm = i; lm = 0; }     // {0..i}
        else             { hm = 7; lm = i - 7; } // {0..i}
        float r = 0.f;
#pragma unroll
        for (int pp = 0; pp < 10; ++pp) {
            float2 gh = G[0][hm][pp];
            float2 gl = G[1][lm][pp];
            float re = gh.x * gl.x - gh.y * gl.y;
            float wgt = ((0x291 >> pp) & 1) ? 1.f : 2.f;
            r = fmaf(wgt, re, r);
        }
        out[b * NQ + i] = r;
    }
}

extern "C" void kernel_launch(void* const* d_in, const int* in_sizes, int n_in,
                              void* d_out, int out_size, void* d_ws, size_t ws_size,
                              hipStream_t stream) {
    const float* z      = (const float*)d_in[0];
    const float* params = (const float*)d_in[1];
    const float* ew     = (const float*)d_in[2];
    float* out          = (float*)d_out;
    const int B = in_sizes[0] / NQ;
    qsim_kernel<<<B, 256, 0, stream>>>(z, params, ew, out);
}